// Round 4
// baseline (251.778 us; speedup 1.0000x reference)
//
#include <hip/hip_runtime.h>

#define BTOT 4096
#define TS 32

typedef __attribute__((ext_vector_type(8))) short bfrag;   // 8 bf16, 16 B
typedef __attribute__((ext_vector_type(4))) float f32x4;

#define HOUT_FLOATS (6*BTOT*64)          // 1,572,864 floats
#define W1BF_OFF    (HOUT_FLOATS*4)      // byte offset of converted w1 in ws

__device__ __forceinline__ short f2bf(float f){
  union { float f; unsigned u; } v; v.f = f;
  unsigned r = v.u + 0x7FFFu + ((v.u >> 16) & 1u);   // RNE
  return (short)(r >> 16);
}
__device__ __forceinline__ float bf2f(short s){
  union { unsigned u; float f; } v; v.u = ((unsigned)(unsigned short)s) << 16; return v.f;
}
__device__ __forceinline__ float sigf(float v){
  return __builtin_amdgcn_rcpf(1.0f + __expf(-v));
}
__device__ __forceinline__ float tanhf_(float v){
  return fmaf(-2.0f, __builtin_amdgcn_rcpf(1.0f + __expf(2.0f * v)), 1.0f);
}

struct LstmP {
  const float* x[6];
  const float* wih[6];
  const float* whh[6];
  const float* bias[6];
  float* hout;        // [6][BTOT][64] fp32
};

struct EpiP {
  const float* hout;
  const short* w1bf;   // [br][hi/lo][64*256] pre-split bf16
  const float* s2;
  const float* w03[2]; const float* b03[2];
  const float* b1[2];
  const float* w2[2];  const float* b2[2];
  float* out;
};

// Convert w1 (both branches) fp32 -> split bf16 planes in ws. grid(2)x256.
__global__ void prep(const float* w1q, const float* w1i, short* dst){
  const int br = blockIdx.x;
  const float* src = br ? w1i : w1q;
  short* hi = dst + br*32768;
  short* lo = hi + 16384;
  for (int i = threadIdx.x; i < 16384; i += 256){
    float f = src[i];
    short h = f2bf(f);
    hi[i] = h;
    lo[i] = f2bf(f - bf2f(h));
  }
}

// Block: run = blockIdx.y, 32 batch elems (2 m-tiles of 16). 4 waves.
// Wave w owns gate-col slice j = 16w + (lane&15) for all 4 gates, both m-tiles.
// Lane holds i,f,g,o of cells (m = mt*16 + 4*(lane>>4) + r, j) in C-regs.
// h round-trips LDS as split bf16 (hi/lo), double-buffered, 1 barrier/step.
__global__ __launch_bounds__(256) void lstm6(LstmP p){
  const int run = blockIdx.y;
  const int b0 = blockIdx.x * 32;
  const int t = threadIdx.x;
  const int wave = t >> 6, lane = t & 63;
  const int i16 = lane & 15, q = lane >> 4;

  // [parity][hi/lo][32 rows * 9 frags]; row stride 9 frags = 72 shorts (pad)
  __shared__ bfrag hbufv[2][2][32*9];
  __shared__ float xs[32*33];           // [m][s], stride 33 (pad)

  const float* __restrict__ whh = p.whh[run];

  // Whh B-fragments, split hi/lo, held in VGPRs (64 VGPRs).
  bfrag Bhi[4][2], Blo[4][2];
#pragma unroll
  for (int g = 0; g < 4; ++g){
    int n = 16*(4*g + wave) + i16;               // whh row (gate index)
    const float* wr = whh + n*64;
#pragma unroll
    for (int ks = 0; ks < 2; ++ks){
      const float* src = wr + 32*ks + 8*q;
      bfrag bh, bl;
#pragma unroll
      for (int j = 0; j < 8; ++j){
        float f = src[j];
        short hi = f2bf(f);
        bh[j] = hi;
        bl[j] = f2bf(f - bf2f(hi));
      }
      Bhi[g][ks] = bh; Blo[g][ks] = bl;
    }
  }
  float wihv[4], bv[4];
#pragma unroll
  for (int g = 0; g < 4; ++g){
    int n = 64*g + 16*wave + i16;
    wihv[g] = p.wih[run][n];
    bv[g]   = p.bias[run][n];
  }
  {
    const float* x = p.x[run] + (size_t)b0 * TS;
    for (int i = t; i < 32*TS; i += 256) xs[(i>>5)*33 + (i&31)] = x[i];
    int* hz = (int*)&hbufv[0][0][0];            // zero parity-0 hi+lo planes
    for (int i = t; i < 2304; i += 256) hz[i] = 0;
  }
  __syncthreads();

  float c[8]  = {0,0,0,0,0,0,0,0};
  float hlast[8];

  for (int s = 0; s < TS; ++s){
    const bfrag* hh = hbufv[s & 1][0];
    const bfrag* hl = hbufv[s & 1][1];
    bfrag ah0[2], ah1[2], al0[2], al1[2];
#pragma unroll
    for (int mt = 0; mt < 2; ++mt){
      const int af = (mt*16 + i16)*9 + q;        // A: m-row = mt*16+i16, k=8q+j
      ah0[mt] = hh[af];
      ah1[mt] = hh[af + 4];
      al0[mt] = hl[af];
      al1[mt] = hl[af + 4];
    }
    float xm[8];
#pragma unroll
    for (int mt = 0; mt < 2; ++mt)
#pragma unroll
      for (int r = 0; r < 4; ++r)
        xm[mt*4+r] = xs[(mt*16 + 4*q + r)*33 + s];

    f32x4 acc[2][4];
#pragma unroll
    for (int mt = 0; mt < 2; ++mt){
#pragma unroll
      for (int g = 0; g < 4; ++g){
#pragma unroll
        for (int r = 0; r < 4; ++r) acc[mt][g][r] = fmaf(xm[mt*4+r], wihv[g], bv[g]);
        acc[mt][g] = __builtin_amdgcn_mfma_f32_16x16x32_bf16(ah0[mt], Bhi[g][0], acc[mt][g], 0,0,0);
        acc[mt][g] = __builtin_amdgcn_mfma_f32_16x16x32_bf16(ah1[mt], Bhi[g][1], acc[mt][g], 0,0,0);
        acc[mt][g] = __builtin_amdgcn_mfma_f32_16x16x32_bf16(al0[mt], Bhi[g][0], acc[mt][g], 0,0,0);
        acc[mt][g] = __builtin_amdgcn_mfma_f32_16x16x32_bf16(al1[mt], Bhi[g][1], acc[mt][g], 0,0,0);
        acc[mt][g] = __builtin_amdgcn_mfma_f32_16x16x32_bf16(ah0[mt], Blo[g][0], acc[mt][g], 0,0,0);
        acc[mt][g] = __builtin_amdgcn_mfma_f32_16x16x32_bf16(ah1[mt], Blo[g][1], acc[mt][g], 0,0,0);
      }
    }

    short* whi = (short*)hbufv[(s+1) & 1][0];
    short* wlo = (short*)hbufv[(s+1) & 1][1];
#pragma unroll
    for (int mt = 0; mt < 2; ++mt){
#pragma unroll
      for (int r = 0; r < 4; ++r){
        float gi = acc[mt][0][r], gf = acc[mt][1][r], gg = acc[mt][2][r], go = acc[mt][3][r];
        float cc = sigf(gf)*c[mt*4+r] + sigf(gi)*tanhf_(gg);
        c[mt*4+r] = cc;
        float hv = sigf(go)*tanhf_(cc);
        hlast[mt*4+r] = hv;
        int off = (mt*16 + 4*q + r)*72 + 16*wave + i16;
        short hi = f2bf(hv);
        whi[off] = hi;
        wlo[off] = f2bf(hv - bf2f(hi));
      }
    }
    __syncthreads();
  }

#pragma unroll
  for (int mt = 0; mt < 2; ++mt)
#pragma unroll
    for (int r = 0; r < 4; ++r){
      int m = mt*16 + 4*q + r, j = 16*wave + i16;
      p.hout[((size_t)run*BTOT + b0 + m)*64 + j] = hlast[mt*4+r];
    }
}

// Epilogue: 16 batch / block, grid (256, 2). Layer1 (256->64) split-bf16 MFMA
// with pre-converted weights; layer2 (64->6) fp32 VALU; log_softmax for i.
__global__ __launch_bounds__(256) void epilogue(EpiP p){
  const int br = blockIdx.y;
  const int b0 = blockIdx.x * 16;
  const int t = threadIdx.x;
  const int wave = t >> 6, lane = t & 63;
  const int i16 = lane & 15, q = lane >> 4;

  __shared__ bfrag hqv_hi[16*33], hqv_lo[16*33];   // [m][k], stride 33 frags
  __shared__ float qv[16*66];                       // layer1 out, stride 66
  __shared__ float iv[16][6];

  const float* hbase = p.hout + (size_t)br*3*BTOT*64;
  {
    short4* dh = (short4*)hqv_hi;
    short4* dl = (short4*)hqv_lo;
    for (int i = t; i < 768; i += 256){
      int run = i >> 8, ii = i & 255;
      int e = ii >> 4, j4 = ii & 15;
      float4 v = *(const float4*)(hbase + ((size_t)run*BTOT + b0 + e)*64 + j4*4);
      short4 h, l;
      short x0 = f2bf(v.x); h.x = x0; l.x = f2bf(v.x - bf2f(x0));
      short x1 = f2bf(v.y); h.y = x1; l.y = f2bf(v.y - bf2f(x1));
      short x2 = f2bf(v.z); h.z = x2; l.z = f2bf(v.z - bf2f(x2));
      short x3 = f2bf(v.w); h.w = x3; l.w = f2bf(v.w - bf2f(x3));
      int o4 = e*66 + run*16 + j4;               // short4 units
      dh[o4] = h;
      dl[o4] = l;
    }
  }
  {
    short* sh = (short*)hqv_hi;
    short* sl = (short*)hqv_lo;
    const float* w03 = p.w03[br];
    const float* b03 = p.b03[br];
    for (int i = t; i < 1024; i += 256){
      int e = i >> 6, jj = i & 63;
      const float* s2r = p.s2 + (size_t)(b0 + e)*3;
      float v = fmaf(s2r[0], w03[jj*3+0],
                fmaf(s2r[1], w03[jj*3+1],
                fmaf(s2r[2], w03[jj*3+2], b03[jj])));
      v = fmaxf(v, 0.0f);
      int off = e*264 + 192 + jj;
      short hi = f2bf(v);
      sh[off] = hi;
      sl[off] = f2bf(v - bf2f(hi));
    }
  }
  __syncthreads();

  // layer1: 3 independent MFMA chains (hi*hi, lo*hi, hi*lo)
  {
    const int n = 16*wave + i16;
    const short* whi = p.w1bf + br*32768 + n*256;
    const short* wlo = whi + 16384;
    f32x4 a0, a1, a2;
    { float bb = p.b1[br][n];
      a0[0]=bb; a0[1]=bb; a0[2]=bb; a0[3]=bb;
      a1[0]=0;  a1[1]=0;  a1[2]=0;  a1[3]=0;
      a2[0]=0;  a2[1]=0;  a2[2]=0;  a2[3]=0; }
#pragma unroll
    for (int ks = 0; ks < 8; ++ks){
      bfrag ah = hqv_hi[i16*33 + 4*ks + q];
      bfrag al = hqv_lo[i16*33 + 4*ks + q];
      bfrag bh = *(const bfrag*)(whi + 32*ks + 8*q);
      bfrag bl = *(const bfrag*)(wlo + 32*ks + 8*q);
      a0 = __builtin_amdgcn_mfma_f32_16x16x32_bf16(ah, bh, a0, 0,0,0);
      a1 = __builtin_amdgcn_mfma_f32_16x16x32_bf16(al, bh, a1, 0,0,0);
      a2 = __builtin_amdgcn_mfma_f32_16x16x32_bf16(ah, bl, a2, 0,0,0);
    }
#pragma unroll
    for (int r = 0; r < 4; ++r)
      qv[(4*q + r)*66 + n] = fmaxf(a0[r] + a1[r] + a2[r], 0.0f);
  }
  __syncthreads();

  if (t < 96){
    int e = t / 6, a = t % 6;
    const float* w2r = p.w2[br] + a*64;
    const float* qe = qv + e*66;
    float acc2 = p.b2[br][a];
#pragma unroll 8
    for (int k = 0; k < 64; ++k) acc2 = fmaf(qe[k], w2r[k], acc2);
    int b = b0 + e;
    if (br == 0){
      p.out[(size_t)b*6 + a] = acc2;                       // q head
    } else {
      float v = fmaxf(acc2, 0.0f);
      iv[e][a] = v;
      p.out[(size_t)2*BTOT*6 + (size_t)b*6 + a] = v;       // i (third output)
    }
  }
  __syncthreads();
  if (br == 1 && t < 16){
    float m = iv[t][0];
    for (int a2 = 1; a2 < 6; ++a2) m = fmaxf(m, iv[t][a2]);
    float ss = 0.0f;
    for (int a2 = 0; a2 < 6; ++a2) ss += __expf(iv[t][a2] - m);
    float ls = __logf(ss);
    int b = b0 + t;
    for (int a2 = 0; a2 < 6; ++a2)
      p.out[(size_t)BTOT*6 + (size_t)b*6 + a2] = iv[t][a2] - m - ls;
  }
}

extern "C" void kernel_launch(void* const* d_in, const int* in_sizes, int n_in,
                              void* d_out, int out_size, void* d_ws, size_t ws_size,
                              hipStream_t stream) {
  const float* x0 = (const float*)d_in[0];
  const float* x1 = (const float*)d_in[1];
  const float* x2 = (const float*)d_in[2];
  const float* s2 = (const float*)d_in[3];

  // ws layout: [0, 6.29MB) hout fp32; [6.29MB, +128KB) split-bf16 w1 planes
  prep<<<dim3(2), 256, 0, stream>>>((const float*)d_in[21], (const float*)d_in[27],
                                    (short*)((char*)d_ws + W1BF_OFF));

  LstmP lp;
  lp.x[0]=x0; lp.x[1]=x1; lp.x[2]=x2; lp.x[3]=x0; lp.x[4]=x1; lp.x[5]=x2;
  const int wbase[6] = {4, 7, 7, 10, 13, 16};   // q00, q01, q01, i00, i01, i02
  for (int r = 0; r < 6; ++r){
    lp.wih[r]  = (const float*)d_in[wbase[r]+0];
    lp.whh[r]  = (const float*)d_in[wbase[r]+1];
    lp.bias[r] = (const float*)d_in[wbase[r]+2];
  }
  lp.hout = (float*)d_ws;

  lstm6<<<dim3(BTOT/32, 6), 256, 0, stream>>>(lp);

  EpiP ep;
  ep.hout = (const float*)d_ws;
  ep.w1bf = (const short*)((char*)d_ws + W1BF_OFF);
  ep.s2 = s2;
  ep.w03[0]=(const float*)d_in[19]; ep.b03[0]=(const float*)d_in[20];
  ep.b1 [0]=(const float*)d_in[22];
  ep.w2 [0]=(const float*)d_in[23]; ep.b2 [0]=(const float*)d_in[24];
  ep.w03[1]=(const float*)d_in[25]; ep.b03[1]=(const float*)d_in[26];
  ep.b1 [1]=(const float*)d_in[28];
  ep.w2 [1]=(const float*)d_in[29]; ep.b2 [1]=(const float*)d_in[30];
  ep.out = (float*)d_out;

  epilogue<<<dim3(BTOT/16, 2), 256, 0, stream>>>(ep);
}

// Round 5
// 231.000 us; speedup vs baseline: 1.0899x; 1.0899x over previous
//
#include <hip/hip_runtime.h>

#define BTOT 4096
#define TS 32

typedef __attribute__((ext_vector_type(8))) short bfrag;   // 8 bf16, 16 B
typedef __attribute__((ext_vector_type(4))) float f32x4;

__device__ __forceinline__ short f2bf(float f){
  union { float f; unsigned u; } v; v.f = f;
  unsigned r = v.u + 0x7FFFu + ((v.u >> 16) & 1u);   // RNE
  return (short)(r >> 16);
}
__device__ __forceinline__ float bf2f(short s){
  union { unsigned u; float f; } v; v.u = ((unsigned)(unsigned short)s) << 16; return v.f;
}

struct LstmP {
  const float* x[6];
  const float* wih[6];
  const float* whh[6];
  const float* bias[6];
  float* hout;        // [6][BTOT][64] fp32
};

struct EpiP {
  const float* hout;
  const float* s2;
  const float* w03[2]; const float* b03[2];
  const float* w1[2];  const float* b1[2];
  const float* w2[2];  const float* b2[2];
  float* out;
};

// Block: run = blockIdx.y, 16 batch elems. 4 waves. (R3 topology: fastest so far.)
// Wave w owns gate-col slice j = 16w + (lane&15) for all 4 gates; lane holds
// i,f,g,o of cell (m = 4*(lane>>4)+r, j) in C-regs. h round-trips LDS as split
// bf16 (hi/lo), double-buffered, 1 barrier/step.
// Cell nonlinearity: 7-transcendental fused form (5 exp + 2 rcp):
//   c' = [c*(1+eg)(1+ei) + (1-eg)(1+ef)] * rcp((1+ef)(1+eg)(1+ei))
//   h  = (1-ec) * rcp((1+ec)(1+eo))
// Bounds: |gate preact| <= ~8.8, |c| <= 32 -> max exp ~ e^64, products < 1e32: finite.
__global__ __launch_bounds__(256) void lstm6(LstmP p){
  const int run = blockIdx.y;
  const int b0 = blockIdx.x * 16;
  const int t = threadIdx.x;
  const int wave = t >> 6, lane = t & 63;
  const int i16 = lane & 15, q = lane >> 4;

  // [parity][hi/lo][16 rows * 9 frags]; row stride 9 frags = 72 shorts (pad)
  __shared__ bfrag hbufv[2][2][16*9];
  __shared__ float xs[16*33];           // [m][s], stride 33 (pad)

  const float* __restrict__ whh = p.whh[run];

  // Whh B-fragments, split hi/lo, held in VGPRs (64 regs).
  bfrag Bhi[4][2], Blo[4][2];
#pragma unroll
  for (int g = 0; g < 4; ++g){
    int n = 16*(4*g + wave) + i16;               // whh row (gate index)
    const float* wr = whh + n*64;
#pragma unroll
    for (int ks = 0; ks < 2; ++ks){
      const float* src = wr + 32*ks + 8*q;
      bfrag bh, bl;
#pragma unroll
      for (int j = 0; j < 8; ++j){
        float f = src[j];
        short hi = f2bf(f);
        bh[j] = hi;
        bl[j] = f2bf(f - bf2f(hi));
      }
      Bhi[g][ks] = bh; Blo[g][ks] = bl;
    }
  }
  float wihv[4], bv[4];
#pragma unroll
  for (int g = 0; g < 4; ++g){
    int n = 64*g + 16*wave + i16;
    wihv[g] = p.wih[run][n];
    bv[g]   = p.bias[run][n];
  }
  {
    const float* x = p.x[run] + (size_t)b0 * TS;
    for (int i = t; i < 16*TS; i += 256) xs[(i>>5)*33 + (i&31)] = x[i];
    int* hz = (int*)&hbufv[0][0][0];            // zero parity-0 hi+lo planes
    for (int i = t; i < 1152; i += 256) hz[i] = 0;
  }
  __syncthreads();

  float c[4] = {0.f,0.f,0.f,0.f};
  float hlast[4] = {0.f,0.f,0.f,0.f};

  for (int s = 0; s < TS; ++s){
    const bfrag* hh = hbufv[s & 1][0];
    const bfrag* hl = hbufv[s & 1][1];
    const int af = i16*9 + q;                    // A: m=lane&15, k=8q+j
    bfrag ah0 = hh[af];
    bfrag ah1 = hh[af + 4];
    bfrag al0 = hl[af];
    bfrag al1 = hl[af + 4];
    float xm[4];
#pragma unroll
    for (int r = 0; r < 4; ++r) xm[r] = xs[(4*q + r)*33 + s];

    f32x4 acc[4];
#pragma unroll
    for (int g = 0; g < 4; ++g){
#pragma unroll
      for (int r = 0; r < 4; ++r) acc[g][r] = fmaf(xm[r], wihv[g], bv[g]);
      acc[g] = __builtin_amdgcn_mfma_f32_16x16x32_bf16(ah0, Bhi[g][0], acc[g], 0,0,0);
      acc[g] = __builtin_amdgcn_mfma_f32_16x16x32_bf16(ah1, Bhi[g][1], acc[g], 0,0,0);
      acc[g] = __builtin_amdgcn_mfma_f32_16x16x32_bf16(al0, Bhi[g][0], acc[g], 0,0,0);
      acc[g] = __builtin_amdgcn_mfma_f32_16x16x32_bf16(al1, Bhi[g][1], acc[g], 0,0,0);
      acc[g] = __builtin_amdgcn_mfma_f32_16x16x32_bf16(ah0, Blo[g][0], acc[g], 0,0,0);
      acc[g] = __builtin_amdgcn_mfma_f32_16x16x32_bf16(ah1, Blo[g][1], acc[g], 0,0,0);
    }

    short* whi = (short*)hbufv[(s+1) & 1][0];
    short* wlo = (short*)hbufv[(s+1) & 1][1];
#pragma unroll
    for (int r = 0; r < 4; ++r){
      float gi = acc[0][r], gf = acc[1][r], gg = acc[2][r], go = acc[3][r];
      // 7-trans fused LSTM cell
      float ef = __expf(-gf);
      float ei = __expf(-gi);
      float eg = __expf(-2.0f*gg);
      float pf = 1.0f + ef;
      float D1 = (1.0f + eg) * (1.0f + ei);
      float num = fmaf(c[r]*D1, 1.0f, (1.0f - eg) * pf);
      float cc = num * __builtin_amdgcn_rcpf(pf * D1);
      c[r] = cc;
      float eo = __expf(-go);
      float ec = __expf(-2.0f*cc);
      float hv = (1.0f - ec) * __builtin_amdgcn_rcpf((1.0f + ec) * (1.0f + eo));
      hlast[r] = hv;
      int off = (4*q + r)*72 + 16*wave + i16;
      short hi = f2bf(hv);
      whi[off] = hi;
      wlo[off] = f2bf(hv - bf2f(hi));
    }
    __syncthreads();
  }

#pragma unroll
  for (int r = 0; r < 4; ++r){
    int m = 4*q + r, j = 16*wave + i16;
    p.hout[((size_t)run*BTOT + b0 + m)*64 + j] = hlast[r];
  }
}

// Epilogue: 16 batch / block, grid (256, 2). Layer1 (256->64) split-bf16 MFMA,
// layer2 (64->6) fp32 VALU, log_softmax for i-branch. (R3 version, measured ~free.)
__global__ __launch_bounds__(256) void epilogue(EpiP p){
  const int br = blockIdx.y;
  const int b0 = blockIdx.x * 16;
  const int t = threadIdx.x;
  const int wave = t >> 6, lane = t & 63;
  const int i16 = lane & 15, q = lane >> 4;

  __shared__ bfrag hqv_hi[16*33], hqv_lo[16*33];   // [m][k], stride 33 frags
  __shared__ float qv[16*66];                       // layer1 out, stride 66
  __shared__ float iv[16][6];

  const float* hbase = p.hout + (size_t)br*3*BTOT*64;
  {
    short4* dh = (short4*)hqv_hi;
    short4* dl = (short4*)hqv_lo;
    for (int i = t; i < 768; i += 256){
      int run = i >> 8, ii = i & 255;
      int e = ii >> 4, j4 = ii & 15;
      float4 v = *(const float4*)(hbase + ((size_t)run*BTOT + b0 + e)*64 + j4*4);
      short4 h, l;
      short x0 = f2bf(v.x); h.x = x0; l.x = f2bf(v.x - bf2f(x0));
      short x1 = f2bf(v.y); h.y = x1; l.y = f2bf(v.y - bf2f(x1));
      short x2 = f2bf(v.z); h.z = x2; l.z = f2bf(v.z - bf2f(x2));
      short x3 = f2bf(v.w); h.w = x3; l.w = f2bf(v.w - bf2f(x3));
      int o4 = e*66 + run*16 + j4;               // short4 units
      dh[o4] = h;
      dl[o4] = l;
    }
  }
  {
    short* sh = (short*)hqv_hi;
    short* sl = (short*)hqv_lo;
    const float* w03 = p.w03[br];
    const float* b03 = p.b03[br];
    for (int i = t; i < 1024; i += 256){
      int e = i >> 6, jj = i & 63;
      const float* s2r = p.s2 + (size_t)(b0 + e)*3;
      float v = fmaf(s2r[0], w03[jj*3+0],
                fmaf(s2r[1], w03[jj*3+1],
                fmaf(s2r[2], w03[jj*3+2], b03[jj])));
      v = fmaxf(v, 0.0f);
      int off = e*264 + 192 + jj;
      short hi = f2bf(v);
      sh[off] = hi;
      sl[off] = f2bf(v - bf2f(hi));
    }
  }
  __syncthreads();

  // layer1: wave owns n-tile = wave -> output col n = 16*wave + i16
  {
    const int n = 16*wave + i16;
    const float* w1r = p.w1[br] + (size_t)n*256;
    f32x4 acc;
    { float bb = p.b1[br][n]; acc[0]=bb; acc[1]=bb; acc[2]=bb; acc[3]=bb; }
#pragma unroll
    for (int ks = 0; ks < 8; ++ks){
      bfrag ah = hqv_hi[i16*33 + 4*ks + q];
      bfrag al = hqv_lo[i16*33 + 4*ks + q];
      const float* src = w1r + 32*ks + 8*q;
      bfrag bh, bl;
#pragma unroll
      for (int j = 0; j < 8; ++j){
        float f = src[j];
        short hi = f2bf(f);
        bh[j] = hi;
        bl[j] = f2bf(f - bf2f(hi));
      }
      acc = __builtin_amdgcn_mfma_f32_16x16x32_bf16(ah, bh, acc, 0,0,0);
      acc = __builtin_amdgcn_mfma_f32_16x16x32_bf16(al, bh, acc, 0,0,0);
      acc = __builtin_amdgcn_mfma_f32_16x16x32_bf16(ah, bl, acc, 0,0,0);
    }
#pragma unroll
    for (int r = 0; r < 4; ++r)
      qv[(4*q + r)*66 + n] = fmaxf(acc[r], 0.0f);
  }
  __syncthreads();

  if (t < 96){
    int e = t / 6, a = t % 6;
    const float* w2r = p.w2[br] + a*64;
    const float* qe = qv + e*66;
    float acc2 = p.b2[br][a];
#pragma unroll 8
    for (int k = 0; k < 64; ++k) acc2 = fmaf(qe[k], w2r[k], acc2);
    int b = b0 + e;
    if (br == 0){
      p.out[(size_t)b*6 + a] = acc2;                       // q head
    } else {
      float v = fmaxf(acc2, 0.0f);
      iv[e][a] = v;
      p.out[(size_t)2*BTOT*6 + (size_t)b*6 + a] = v;       // i (third output)
    }
  }
  __syncthreads();
  if (br == 1 && t < 16){
    float m = iv[t][0];
    for (int a2 = 1; a2 < 6; ++a2) m = fmaxf(m, iv[t][a2]);
    float ss = 0.0f;
    for (int a2 = 0; a2 < 6; ++a2) ss += __expf(iv[t][a2] - m);
    float ls = __logf(ss);
    int b = b0 + t;
    for (int a2 = 0; a2 < 6; ++a2)
      p.out[(size_t)BTOT*6 + (size_t)b*6 + a2] = iv[t][a2] - m - ls;
  }
}

extern "C" void kernel_launch(void* const* d_in, const int* in_sizes, int n_in,
                              void* d_out, int out_size, void* d_ws, size_t ws_size,
                              hipStream_t stream) {
  const float* x0 = (const float*)d_in[0];
  const float* x1 = (const float*)d_in[1];
  const float* x2 = (const float*)d_in[2];
  const float* s2 = (const float*)d_in[3];

  LstmP lp;
  lp.x[0]=x0; lp.x[1]=x1; lp.x[2]=x2; lp.x[3]=x0; lp.x[4]=x1; lp.x[5]=x2;
  const int wbase[6] = {4, 7, 7, 10, 13, 16};   // q00, q01, q01, i00, i01, i02
  for (int r = 0; r < 6; ++r){
    lp.wih[r]  = (const float*)d_in[wbase[r]+0];
    lp.whh[r]  = (const float*)d_in[wbase[r]+1];
    lp.bias[r] = (const float*)d_in[wbase[r]+2];
  }
  lp.hout = (float*)d_ws;   // 6*4096*64 fp32 = 6.29 MB

  lstm6<<<dim3(BTOT/16, 6), 256, 0, stream>>>(lp);

  EpiP ep;
  ep.hout = (const float*)d_ws;
  ep.s2 = s2;
  ep.w03[0]=(const float*)d_in[19]; ep.b03[0]=(const float*)d_in[20];
  ep.w1 [0]=(const float*)d_in[21]; ep.b1 [0]=(const float*)d_in[22];
  ep.w2 [0]=(const float*)d_in[23]; ep.b2 [0]=(const float*)d_in[24];
  ep.w03[1]=(const float*)d_in[25]; ep.b03[1]=(const float*)d_in[26];
  ep.w1 [1]=(const float*)d_in[27]; ep.b1 [1]=(const float*)d_in[28];
  ep.w2 [1]=(const float*)d_in[29]; ep.b2 [1]=(const float*)d_in[30];
  ep.out = (float*)d_out;

  epilogue<<<dim3(BTOT/16, 2), 256, 0, stream>>>(ep);
}